// Round 2
// baseline (38.215 us; speedup 1.0000x reference)
//
#include <hip/hip_runtime.h>
#include <hip/hip_bf16.h>

#define DD 256
#define M_ROWS 16384

typedef float f32x4 __attribute__((ext_vector_type(4)));
typedef __bf16 bf16x8 __attribute__((ext_vector_type(8)));

// ---------------------------------------------------------------------------
// Fused: Wc = Wout @ Wv (bf16 out) and bc = bout + Wout @ bv.
// 256 blocks x 256 threads; block i computes row i of Wc and bc[i].
// Wv = rows [2D,3D) of Wqkv, bv = bqkv[2D:3D].
// ---------------------------------------------------------------------------
__global__ __launch_bounds__(256) void wc_bc_kernel(
    const float* __restrict__ Wqkv, const float* __restrict__ bqkv,
    const float* __restrict__ Wout, const float* __restrict__ bout,
    __bf16* __restrict__ Wc, float* __restrict__ bc) {
  const int i = blockIdx.x;
  const int j = threadIdx.x;
  const float* __restrict__ Wv = Wqkv + 2 * DD * DD;
  const float* __restrict__ wrow = Wout + (size_t)i * DD;

  // bc partial: thread j contributes Wout[i][j] * bv[j]
  float p = wrow[j] * bqkv[2 * DD + j];
#pragma unroll
  for (int off = 32; off > 0; off >>= 1) p += __shfl_down(p, off);
  __shared__ float red[4];
  if ((j & 63) == 0) red[j >> 6] = p;

  // Wc row: thread j computes sum_d Wout[i][d] * Wv[d][j]
  // wrow[d] is wave-uniform (scalar loads); Wv loads coalesced (1KB/iter).
  float a0 = 0.f, a1 = 0.f, a2 = 0.f, a3 = 0.f;
#pragma unroll 4
  for (int d = 0; d < DD; d += 4) {
    a0 += wrow[d + 0] * Wv[(size_t)(d + 0) * DD + j];
    a1 += wrow[d + 1] * Wv[(size_t)(d + 1) * DD + j];
    a2 += wrow[d + 2] * Wv[(size_t)(d + 2) * DD + j];
    a3 += wrow[d + 3] * Wv[(size_t)(d + 3) * DD + j];
  }
  Wc[(size_t)i * DD + j] = (__bf16)((a0 + a1) + (a2 + a3));

  __syncthreads();
  if (j == 0) bc[i] = bout[i] + red[0] + red[1] + red[2] + red[3];
}

// ---------------------------------------------------------------------------
// out = x + x @ Wc^T + bc.
// Both operands k-contiguous row-major -> direct 16B MFMA fragment loads.
// Block = 256 threads = 4 waves; block covers 16 rows x 256 cols
// (wave w -> cols 64w..64w+63). Grid = 16384/16 = 1024 blocks
// -> 4096 waves = 4 waves/SIMD for latency hiding.
// ---------------------------------------------------------------------------
__global__ __launch_bounds__(256) void knn_attn_main(
    const float* __restrict__ x, const __bf16* __restrict__ Wc,
    const float* __restrict__ bc, float* __restrict__ out) {
  const int t = threadIdx.x;
  const int w = t >> 6;   // wave -> column group
  const int l = t & 63;   // lane
  const int r0 = blockIdx.x * 16;
  const int c0 = w * 64;
  const int lr = l & 15;        // row-in-tile for A/B fragments
  const int lk = (l >> 4) * 8;  // k-offset within a 32-wide k-slice

  // A fragments: 8 k-slices, fp32 -> bf16 inline.
  bf16x8 a[8];
  const float* xr = x + (size_t)(r0 + lr) * DD + lk;
#pragma unroll
  for (int ks = 0; ks < 8; ++ks) {
    f32x4 lo = *(const f32x4*)(xr + ks * 32);
    f32x4 hi = *(const f32x4*)(xr + ks * 32 + 4);
    bf16x8 v;
#pragma unroll
    for (int jj = 0; jj < 4; ++jj) {
      v[jj] = (__bf16)lo[jj];
      v[4 + jj] = (__bf16)hi[jj];
    }
    a[ks] = v;
  }

  f32x4 acc[4] = {};

#pragma unroll
  for (int ct = 0; ct < 4; ++ct) {
    const __bf16* wr = Wc + (size_t)(c0 + ct * 16 + lr) * DD + lk;
#pragma unroll
    for (int ks = 0; ks < 8; ++ks) {
      bf16x8 b = *(const bf16x8*)(wr + ks * 32);  // L2-resident Wc
      acc[ct] = __builtin_amdgcn_mfma_f32_16x16x32_bf16(a[ks], b, acc[ct], 0, 0, 0);
    }
  }

  // Epilogue: C/D layout col = lane&15, row = (lane>>4)*4 + reg (m89/m91).
  const int orow = (l >> 4) * 4;
  const int ocol = l & 15;
#pragma unroll
  for (int ct = 0; ct < 4; ++ct) {
    const int c = c0 + ct * 16 + ocol;
    const float bias = bc[c];
#pragma unroll
    for (int rg = 0; rg < 4; ++rg) {
      const size_t idx = (size_t)(r0 + orow + rg) * DD + c;
      out[idx] = acc[ct][rg] + x[idx] + bias;
    }
  }
}

extern "C" void kernel_launch(void* const* d_in, const int* in_sizes, int n_in,
                              void* d_out, int out_size, void* d_ws, size_t ws_size,
                              hipStream_t stream) {
  const float* x = (const float*)d_in[0];
  const float* Wqkv = (const float*)d_in[1];
  const float* bqkv = (const float*)d_in[2];
  const float* Wout = (const float*)d_in[3];
  const float* bout = (const float*)d_in[4];
  float* out = (float*)d_out;

  __bf16* Wc = (__bf16*)d_ws;                                   // 128 KiB
  float* bc = (float*)((char*)d_ws + DD * DD * sizeof(__bf16)); // +1 KiB

  wc_bc_kernel<<<DD, 256, 0, stream>>>(Wqkv, bqkv, Wout, bout, Wc, bc);
  knn_attn_main<<<M_ROWS / 16, 256, 0, stream>>>(x, Wc, bc, out);
}